// Round 3
// baseline (217.725 us; speedup 1.0000x reference)
//
#include <hip/hip_runtime.h>
#include <stdint.h>
#include <math.h>

#define BB 2
#define SS 2048
#define DM 1024
#define NH 16
#define HD 64
#define MTOT (BB*SS)

typedef __bf16 bf16x8 __attribute__((ext_vector_type(8)));
typedef float  f32x4  __attribute__((ext_vector_type(4)));
typedef uint32_t u32x4 __attribute__((ext_vector_type(4)));

__device__ __forceinline__ unsigned short f2bf(float f) {
  __bf16 h = (__bf16)f;                 // RNE; compiler packs to v_cvt_pk_bf16_f32
  return __builtin_bit_cast(unsigned short, h);
}

__device__ __forceinline__ bf16x8 ldsv8(const unsigned short* p) {
  return __builtin_bit_cast(bf16x8, *(const u32x4*)p);
}

__device__ __forceinline__ void gl16(const void* g, void* l) {
  __builtin_amdgcn_global_load_lds(
      (const __attribute__((address_space(1))) uint32_t*)g,
      (__attribute__((address_space(3))) uint32_t*)l, 16, 0, 0);
}

#define MFMA16(a,b,c) __builtin_amdgcn_mfma_f32_16x16x32_bf16((a),(b),(c),0,0,0)

// gate/softmax constants
#define C_NEG5L2E  (-7.213475204444817f)   // -5*log2(e)
#define C_L2E      (1.4426950408889634f)   // log2(e)
#define C_18L2E    (25.968510736001341f)   // 18*log2(e)

// ---------------- prep: quaternion weight build + bf16 conversion ----------------
__global__ __launch_bounds__(256) void prep_w(
    const float* __restrict__ wqr, const float* __restrict__ wqi,
    const float* __restrict__ wqj, const float* __restrict__ wqk,
    const float* __restrict__ wkr, const float* __restrict__ wki,
    const float* __restrict__ wkj, const float* __restrict__ wkk,
    const float* __restrict__ wv,  const float* __restrict__ wo,
    unsigned short* __restrict__ Wq, unsigned short* __restrict__ Wk,
    unsigned short* __restrict__ Wv, unsigned short* __restrict__ Wo)
{
  const int idx = blockIdx.x * 256 + threadIdx.x;   // over 1024*1024
  const int o = idx >> 10, i = idx & 1023;
  const int br = o >> 8, bc = i >> 8;
  const int ro = o & 255, ci = i & 255;
  const int comp[4][4] = {{0,1,2,3},{1,0,3,2},{2,3,0,1},{3,2,1,0}};
  const float sgn[4][4] = {{1.f,-1.f,-1.f,-1.f},{1.f,1.f,-1.f,1.f},{1.f,1.f,1.f,-1.f},{1.f,-1.f,1.f,1.f}};
  const float* pq[4] = {wqr, wqi, wqj, wqk};
  const float* pk[4] = {wkr, wki, wkj, wkk};
  const int c_ = comp[br][bc];
  const float s_ = sgn[br][bc];
  const int pidx = ro * 256 + ci;
  Wq[idx] = f2bf(s_ * pq[c_][pidx]);
  Wk[idx] = f2bf(s_ * pk[c_][pidx]);
  Wv[idx] = f2bf(wv[idx]);
  Wo[idx] = f2bf(wo[idx]);
}

// ---------------- prep: per-(b,n) spike threshold -> (kthr, limk) ----------------
__global__ __launch_bounds__(256) void prep_thr(
    const float* __restrict__ density, const float* __restrict__ dm1w,
    const float* __restrict__ dm1b, const float* __restrict__ dm2w,
    const float* __restrict__ dm2b, const float* __restrict__ thr_s,
    const int* __restrict__ mask, float2* __restrict__ out)
{
  const int i = blockIdx.x * 256 + threadIdx.x;  // over B*S = 4096
  if (i >= BB * SS) return;
  const float x0 = density[i*3+0], x1 = density[i*3+1], x2 = density[i*3+2];
  const float base = log1pf(expf(thr_s[0]));     // softplus
  float acc = dm2b[0];
  #pragma unroll
  for (int j = 0; j < 16; ++j) {
    const float hj = dm1w[j*3+0]*x0 + dm1w[j*3+1]*x1 + dm1w[j*3+2]*x2 + dm1b[j];
    const float ge = 0.5f * hj * (1.0f + erff(hj * 0.70710678118654752f)); // exact gelu
    acc += dm2w[j] * ge;
  }
  const float thr = base + 0.1f * acc;
  out[i] = make_float2(thr * (-C_NEG5L2E),            // +5*log2e*thr (exp2 arg offset)
                       mask[i] ? 1e30f : -30.0f);     // mask limit for min
}

// ---------------- GEMM: C(M=4096,N=1024) = A(M,K=1024) @ W(N,K)^T + bias ----------------
// Batched over blockIdx.y (z). AMODE 0: A fp32 reg-staged+converted; 1: A bf16 via global_load_lds.
// omode per z: 0 = bf16 row-major; 1 = bf16 per-head-transposed V^T (H,B,hd,S); 2 = fp32 row-major.
struct GemmArgs {
  const void* A[3];
  const unsigned short* W[3];
  const float* bias[3];
  void* out[3];
  float scale[3];
  int omode[3];
};

template<int AMODE>
__global__ __launch_bounds__(256) void gemm_fused(GemmArgs args)
{
  __shared__ __align__(16) unsigned short lA[128*64];
  __shared__ __align__(16) unsigned short lB[128*64];
  const int z = blockIdx.y;
  const unsigned short* W = args.W[z];
  const int tid = threadIdx.x;
  const int wid = tid >> 6, lane = tid & 63;
  const int l15 = lane & 15, l4 = lane >> 4;
  const int bm = blockIdx.x >> 3, bn = blockIdx.x & 7;
  const int row0 = bm * 128, col0 = bn * 128;
  const int wm = (wid >> 1) * 64, wn = (wid & 1) * 64;

  // global_load_lds staging: 1024 16B-chunks per 128x64 tile; wave w, inst i covers
  // chunks [(w*4+i)*64, +64). LDS dest linear; source pre-swizzled so that LDS
  // element layout is r*64 + ((j*8) ^ ((r&7)<<3)).
  const unsigned short* gB[4];
  unsigned short* dB[4];
  const unsigned short* gA1[4];
  unsigned short* dA1[4];
  #pragma unroll
  for (int i = 0; i < 4; ++i) {
    const int c = (wid * 4 + i) * 64 + lane;
    const int r = c >> 3, jx = c & 7, j = jx ^ (r & 7);
    gB[i] = W + (col0 + r) * 1024 + j * 8;
    dB[i] = &lB[(wid * 4 + i) * 512];
    if (AMODE == 1) {
      gA1[i] = (const unsigned short*)args.A[z] + (row0 + r) * 1024 + j * 8;
      dA1[i] = &lA[(wid * 4 + i) * 512];
    }
  }

  f32x4 acc[4][4];
  #pragma unroll
  for (int i = 0; i < 4; ++i)
    #pragma unroll
    for (int j = 0; j < 4; ++j) acc[i][j] = (f32x4){0.f,0.f,0.f,0.f};

  for (int kt = 0; kt < 16; ++kt) {
    const int k0 = kt * 64;
    // issue async B staging first (latency hides under A VALU work)
    #pragma unroll
    for (int i = 0; i < 4; ++i) gl16(gB[i] + k0, dB[i]);
    if (AMODE == 1) {
      #pragma unroll
      for (int i = 0; i < 4; ++i) gl16(gA1[i] + k0, dA1[i]);
    } else {
      #pragma unroll
      for (int it = 0; it < 4; ++it) {
        const int c = tid + it * 256;
        const int r = c >> 3, j = c & 7;
        const int didx = r * 64 + ((j * 8) ^ ((r & 7) << 3));
        const float* src = (const float*)args.A[z] + (row0 + r) * 1024 + k0 + j * 8;
        const float4 f0 = *(const float4*)src;
        const float4 f1 = *(const float4*)(src + 4);
        union { unsigned short us[8]; u32x4 v; } tmp;
        tmp.us[0]=f2bf(f0.x); tmp.us[1]=f2bf(f0.y); tmp.us[2]=f2bf(f0.z); tmp.us[3]=f2bf(f0.w);
        tmp.us[4]=f2bf(f1.x); tmp.us[5]=f2bf(f1.y); tmp.us[6]=f2bf(f1.z); tmp.us[7]=f2bf(f1.w);
        *(u32x4*)&lA[didx] = tmp.v;
      }
    }
    __syncthreads();
    #pragma unroll
    for (int kk = 0; kk < 2; ++kk) {
      const int kl = kk * 32 + l4 * 8;
      bf16x8 af[4], bfb[4];
      #pragma unroll
      for (int mi = 0; mi < 4; ++mi) {
        const int r = wm + mi * 16 + l15;
        af[mi] = ldsv8(&lA[r * 64 + (kl ^ ((r & 7) << 3))]);
      }
      #pragma unroll
      for (int nj = 0; nj < 4; ++nj) {
        const int r = wn + nj * 16 + l15;
        bfb[nj] = ldsv8(&lB[r * 64 + (kl ^ ((r & 7) << 3))]);
      }
      #pragma unroll
      for (int mi = 0; mi < 4; ++mi)
        #pragma unroll
        for (int nj = 0; nj < 4; ++nj)
          acc[mi][nj] = MFMA16(af[mi], bfb[nj], acc[mi][nj]);
    }
    __syncthreads();
  }

  // epilogue: C/D layout col = lane&15, row = (lane>>4)*4 + e
  const int om = args.omode[z];
  const float sc = args.scale[z];
  void* Cptr = args.out[z];
  #pragma unroll
  for (int nj = 0; nj < 4; ++nj) {
    const int c = col0 + wn + nj * 16 + l15;
    const float bv_ = args.bias[z][c];
    #pragma unroll
    for (int mi = 0; mi < 4; ++mi) {
      const int rb = row0 + wm + mi * 16 + l4 * 4;
      #pragma unroll
      for (int e = 0; e < 4; ++e) {
        const float val = (acc[mi][nj][e] + bv_) * sc;
        const int r = rb + e;
        if (om == 0) {
          ((unsigned short*)Cptr)[r * 1024 + c] = f2bf(val);
        } else if (om == 2) {
          ((float*)Cptr)[r * 1024 + c] = val;
        } else {
          const int h = c >> 6, d = c & 63, b = r >> 11, s = r & 2047;
          ((unsigned short*)Cptr)[((h * BB + b) * HD + d) * SS + s] = f2bf(val);
        }
      }
    }
  }
}

// ---------------- flash attention with spike gate (fixed-max softmax) ----------------
__global__ __launch_bounds__(256) void attn_kernel(
    const unsigned short* __restrict__ qg, const unsigned short* __restrict__ kg,
    const unsigned short* __restrict__ vT, const float2* __restrict__ klim,
    const int* __restrict__ mask, unsigned short* __restrict__ outg)
{
  __shared__ __align__(16) unsigned short lK[2][64*64];
  __shared__ __align__(16) unsigned short lV[2][64*64];
  __shared__ __align__(16) unsigned short lP[4][16*64];
  const int tid = threadIdx.x;
  const int wid = tid >> 6, lane = tid & 63;
  const int l15 = lane & 15, l4 = lane >> 4;
  const int qb = blockIdx.x & 31, hb = blockIdx.x >> 5;
  const int h = hb >> 1, b = hb & 1;
  const int qr0 = qb * 64 + wid * 16;

  // staging geometry: 512 chunks of 8 bf16 over a 64x64 tile, 2 per thread
  const int c0r = tid >> 3, c0j = (tid & 7) * 8;
  const int c1r = c0r + 32;
  const int dK0 = c0r * 64 + (c0j ^ ((c0r & 7) << 3));
  const int dK1 = c1r * 64 + (c0j ^ ((c1r & 7) << 3));
  const unsigned short* kbase = kg + (b * SS) * DM + h * HD;
  const unsigned short* vbase = vT + ((h * BB + b) * HD) * SS;
  const float2* klimb = klim + b * SS;

  // Q fragments in registers (A-frag: row=lane%16, k=(lane>>4)*8); Q pre-scaled by 0.25
  bf16x8 aq[2];
  {
    const unsigned short* qs = qg + (b * SS + qr0 + l15) * DM + h * HD + l4 * 8;
    aq[0] = __builtin_bit_cast(bf16x8, *(const u32x4*)qs);
    aq[1] = __builtin_bit_cast(bf16x8, *(const u32x4*)(qs + 32));
  }
  float limq[4];
  #pragma unroll
  for (int e = 0; e < 4; ++e)
    limq[e] = mask[b * SS + qr0 + l4 * 4 + e] ? 1e30f : -30.0f;

  float lrun[4] = {0.f, 0.f, 0.f, 0.f};
  f32x4 o[4];
  #pragma unroll
  for (int d = 0; d < 4; ++d) o[d] = (f32x4){0.f,0.f,0.f,0.f};

  unsigned short* lPw = lP[wid];

  // prologue: stage tile 0
  u32x4 kr0 = *(const u32x4*)(kbase + c0r * DM + c0j);
  u32x4 kr1 = *(const u32x4*)(kbase + c1r * DM + c0j);
  u32x4 vr0 = *(const u32x4*)(vbase + c0r * SS + c0j);
  u32x4 vr1 = *(const u32x4*)(vbase + c1r * SS + c0j);
  *(u32x4*)&lK[0][dK0] = kr0;
  *(u32x4*)&lK[0][dK1] = kr1;
  *(u32x4*)&lV[0][dK0] = vr0;
  *(u32x4*)&lV[0][dK1] = vr1;
  __syncthreads();

  for (int kb = 0; kb < 32; ++kb) {
    const int cur = kb & 1;
    const unsigned short* lKc = lK[cur];
    const unsigned short* lVc = lV[cur];
    const int n0g = kb * 64;

    // prefetch next tile into regs (hidden under compute)
    if (kb < 31) {
      const int n2 = n0g + 64;
      kr0 = *(const u32x4*)(kbase + (n2 + c0r) * DM + c0j);
      kr1 = *(const u32x4*)(kbase + (n2 + c1r) * DM + c0j);
      vr0 = *(const u32x4*)(vbase + c0r * SS + n2 + c0j);
      vr1 = *(const u32x4*)(vbase + c1r * SS + n2 + c0j);
    }

    // per-key (kthr, limk)
    float2 kl[4];
    #pragma unroll
    for (int cf = 0; cf < 4; ++cf) kl[cf] = klimb[n0g + cf * 16 + l15];

    // S = Q @ K^T (per wave: 16 rows x 64 cols)
    f32x4 sv[4];
    __builtin_amdgcn_s_setprio(1);
    #pragma unroll
    for (int cf = 0; cf < 4; ++cf) {
      f32x4 a = (f32x4){0.f,0.f,0.f,0.f};
      #pragma unroll
      for (int kk = 0; kk < 2; ++kk) {
        const int n = cf * 16 + l15;
        bf16x8 bk_ = ldsv8(&lKc[n * 64 + ((kk * 32 + l4 * 8) ^ ((n & 7) << 3))]);
        a = MFMA16(aq[kk], bk_, a);
      }
      sv[cf] = a;
    }
    __builtin_amdgcn_s_setprio(0);

    // spike gate + mask + fixed-max softmax numerator
    float pvv[4][4];
    #pragma unroll
    for (int cf = 0; cf < 4; ++cf) {
      #pragma unroll
      for (int e = 0; e < 4; ++e) {
        float s = fminf(fmaxf(sv[cf][e], -6.f), 6.f);
        const float t = __builtin_amdgcn_exp2f(fmaf(s, C_NEG5L2E, kl[cf].x));
        const float g = __builtin_amdgcn_rcpf(1.f + t);
        float md = fmaf(s + s, g, s);                       // s*(1+2g) in [-18,18]
        md = fminf(md, fminf(kl[cf].y, limq[e]));           // mask -> -30
        const float p = __builtin_amdgcn_exp2f(fmaf(md, C_L2E, -C_18L2E)); // exp(md-18)
        pvv[cf][e] = p;
        lrun[e] += p;
      }
    }

    // P -> per-wave LDS (swizzled), then A-fragments for PV
    #pragma unroll
    for (int cf = 0; cf < 4; ++cf)
      #pragma unroll
      for (int e = 0; e < 4; ++e) {
        const int rr = l4 * 4 + e, cc = cf * 16 + l15;
        lPw[rr * 64 + (cc ^ ((rr & 7) << 3))] = f2bf(pvv[cf][e]);
      }
    asm volatile("s_waitcnt lgkmcnt(0)" ::: "memory");
    __builtin_amdgcn_sched_barrier(0);

    bf16x8 pa[2];
    #pragma unroll
    for (int kk = 0; kk < 2; ++kk)
      pa[kk] = ldsv8(&lPw[l15 * 64 + ((kk * 32 + l4 * 8) ^ ((l15 & 7) << 3))]);

    __builtin_amdgcn_s_setprio(1);
    #pragma unroll
    for (int df = 0; df < 4; ++df) {
      #pragma unroll
      for (int kk = 0; kk < 2; ++kk) {
        const int d = df * 16 + l15;
        bf16x8 bv_ = ldsv8(&lVc[d * 64 + ((kk * 32 + l4 * 8) ^ ((d & 7) << 3))]);
        o[df] = MFMA16(pa[kk], bv_, o[df]);
      }
    }
    __builtin_amdgcn_s_setprio(0);

    // write next tile to the other LDS buffer
    if (kb < 31) {
      const int nxt = cur ^ 1;
      *(u32x4*)&lK[nxt][dK0] = kr0;
      *(u32x4*)&lK[nxt][dK1] = kr1;
      *(u32x4*)&lV[nxt][dK0] = vr0;
      *(u32x4*)&lV[nxt][dK1] = vr1;
    }
    __syncthreads();
  }

  // final: reduce row sums across the 16 lanes of each l4 group, normalize, store
  #pragma unroll
  for (int e = 0; e < 4; ++e) {
    float ls = lrun[e];
    ls += __shfl_xor(ls, 1);
    ls += __shfl_xor(ls, 2);
    ls += __shfl_xor(ls, 4);
    ls += __shfl_xor(ls, 8);
    const float rl = __builtin_amdgcn_rcpf(ls);
    const int r = qr0 + l4 * 4 + e;
    #pragma unroll
    for (int df = 0; df < 4; ++df) {
      outg[(b * SS + r) * DM + h * HD + df * 16 + l15] = f2bf(o[df][e] * rl);
    }
  }
}

// ---------------- launcher ----------------
extern "C" void kernel_launch(void* const* d_in, const int* in_sizes, int n_in,
                              void* d_out, int out_size, void* d_ws, size_t ws_size,
                              hipStream_t stream)
{
  const float* query   = (const float*)d_in[0];
  const float* key_in  = (const float*)d_in[1];
  const float* value   = (const float*)d_in[2];
  const int*   mask    = (const int*)d_in[3];
  const float* density = (const float*)d_in[4];
  const float* wq_r = (const float*)d_in[5];
  const float* wq_i = (const float*)d_in[6];
  const float* wq_j = (const float*)d_in[7];
  const float* wq_k = (const float*)d_in[8];
  const float* bq   = (const float*)d_in[9];
  const float* wk_r = (const float*)d_in[10];
  const float* wk_i = (const float*)d_in[11];
  const float* wk_j = (const float*)d_in[12];
  const float* wk_k = (const float*)d_in[13];
  const float* bk   = (const float*)d_in[14];
  const float* wv   = (const float*)d_in[15];
  const float* bv   = (const float*)d_in[16];
  const float* wo   = (const float*)d_in[17];
  const float* bo   = (const float*)d_in[18];
  const float* thrs = (const float*)d_in[19];
  const float* dm1w = (const float*)d_in[20];
  const float* dm1b = (const float*)d_in[21];
  const float* dm2w = (const float*)d_in[22];
  const float* dm2b = (const float*)d_in[23];

  char* ws = (char*)d_ws;
  unsigned short* Wq  = (unsigned short*)(ws + ((size_t)0 << 20));
  unsigned short* Wk  = (unsigned short*)(ws + ((size_t)2 << 20));
  unsigned short* Wv  = (unsigned short*)(ws + ((size_t)4 << 20));
  unsigned short* Wo  = (unsigned short*)(ws + ((size_t)6 << 20));
  unsigned short* qbf = (unsigned short*)(ws + ((size_t)8 << 20));
  unsigned short* kbf = (unsigned short*)(ws + ((size_t)16 << 20));
  unsigned short* vT  = (unsigned short*)(ws + ((size_t)24 << 20));
  unsigned short* att = (unsigned short*)(ws + ((size_t)32 << 20));
  float2* klim        = (float2*)(ws + ((size_t)40 << 20));

  prep_w<<<4096, 256, 0, stream>>>(wq_r, wq_i, wq_j, wq_k,
                                   wk_r, wk_i, wk_j, wk_k,
                                   wv, wo, Wq, Wk, Wv, Wo);
  prep_thr<<<16, 256, 0, stream>>>(density, dm1w, dm1b, dm2w, dm2b, thrs, mask, klim);

  GemmArgs qkv;
  qkv.A[0] = query;  qkv.W[0] = Wq; qkv.bias[0] = bq; qkv.out[0] = qbf; qkv.scale[0] = 0.25f; qkv.omode[0] = 0;
  qkv.A[1] = key_in; qkv.W[1] = Wk; qkv.bias[1] = bk; qkv.out[1] = kbf; qkv.scale[1] = 1.0f;  qkv.omode[1] = 0;
  qkv.A[2] = value;  qkv.W[2] = Wv; qkv.bias[2] = bv; qkv.out[2] = vT;  qkv.scale[2] = 1.0f;  qkv.omode[2] = 1;
  gemm_fused<0><<<dim3(256, 3), 256, 0, stream>>>(qkv);

  attn_kernel<<<1024, 256, 0, stream>>>(qbf, kbf, vT, klim, mask, att);

  GemmArgs og;
  og.A[0] = att; og.W[0] = Wo; og.bias[0] = bo; og.out[0] = d_out; og.scale[0] = 1.0f; og.omode[0] = 2;
  og.A[1] = att; og.W[1] = Wo; og.bias[1] = bo; og.out[1] = d_out; og.scale[1] = 1.0f; og.omode[1] = 2;
  og.A[2] = att; og.W[2] = Wo; og.bias[2] = bo; og.out[2] = d_out; og.scale[2] = 1.0f; og.omode[2] = 2;
  gemm_fused<1><<<dim3(256, 1), 256, 0, stream>>>(og);
}

// Round 4
// 190.256 us; speedup vs baseline: 1.1444x; 1.1444x over previous
//
#include <hip/hip_runtime.h>
#include <stdint.h>
#include <math.h>

#define BB 2
#define SS 2048
#define DM 1024
#define NH 16
#define HD 64
#define MTOT (BB*SS)

typedef __bf16 bf16x8 __attribute__((ext_vector_type(8)));
typedef float  f32x4  __attribute__((ext_vector_type(4)));
typedef uint32_t u32x4 __attribute__((ext_vector_type(4)));

__device__ __forceinline__ unsigned short f2bf(float f) {
  __bf16 h = (__bf16)f;                 // RNE; compiler packs to v_cvt_pk_bf16_f32
  return __builtin_bit_cast(unsigned short, h);
}

__device__ __forceinline__ bf16x8 ldsv8(const unsigned short* p) {
  return __builtin_bit_cast(bf16x8, *(const u32x4*)p);
}

__device__ __forceinline__ void gl16(const void* g, void* l) {
  __builtin_amdgcn_global_load_lds(
      (const __attribute__((address_space(1))) uint32_t*)g,
      (__attribute__((address_space(3))) uint32_t*)l, 16, 0, 0);
}

#define MFMA16(a,b,c) __builtin_amdgcn_mfma_f32_16x16x32_bf16((a),(b),(c),0,0,0)

// gate/softmax constants
#define C_NEG5L2E  (-7.213475204444817f)   // -5*log2(e)
#define C_L2E      (1.4426950408889634f)   // log2(e)
#define C_18L2E    (25.968510736001341f)   // 18*log2(e)

// ---------------- prep: fp32 -> bf16 convert of q/k/v activations ----------------
__global__ __launch_bounds__(256) void cvt_bf16(
    const float* __restrict__ a, const float* __restrict__ b, const float* __restrict__ c,
    unsigned short* __restrict__ ao, unsigned short* __restrict__ bo, unsigned short* __restrict__ co)
{
  const int i8 = (blockIdx.x * 256 + threadIdx.x) * 8;   // grid covers 4194304 elems
  {
    const float4 f0 = *(const float4*)(a + i8);
    const float4 f1 = *(const float4*)(a + i8 + 4);
    union { unsigned short us[8]; u32x4 v; } t;
    t.us[0]=f2bf(f0.x); t.us[1]=f2bf(f0.y); t.us[2]=f2bf(f0.z); t.us[3]=f2bf(f0.w);
    t.us[4]=f2bf(f1.x); t.us[5]=f2bf(f1.y); t.us[6]=f2bf(f1.z); t.us[7]=f2bf(f1.w);
    *(u32x4*)(ao + i8) = t.v;
  }
  {
    const float4 f0 = *(const float4*)(b + i8);
    const float4 f1 = *(const float4*)(b + i8 + 4);
    union { unsigned short us[8]; u32x4 v; } t;
    t.us[0]=f2bf(f0.x); t.us[1]=f2bf(f0.y); t.us[2]=f2bf(f0.z); t.us[3]=f2bf(f0.w);
    t.us[4]=f2bf(f1.x); t.us[5]=f2bf(f1.y); t.us[6]=f2bf(f1.z); t.us[7]=f2bf(f1.w);
    *(u32x4*)(bo + i8) = t.v;
  }
  {
    const float4 f0 = *(const float4*)(c + i8);
    const float4 f1 = *(const float4*)(c + i8 + 4);
    union { unsigned short us[8]; u32x4 v; } t;
    t.us[0]=f2bf(f0.x); t.us[1]=f2bf(f0.y); t.us[2]=f2bf(f0.z); t.us[3]=f2bf(f0.w);
    t.us[4]=f2bf(f1.x); t.us[5]=f2bf(f1.y); t.us[6]=f2bf(f1.z); t.us[7]=f2bf(f1.w);
    *(u32x4*)(co + i8) = t.v;
  }
}

// ---------------- prep: quaternion weight build + bf16 conversion ----------------
__global__ __launch_bounds__(256) void prep_w(
    const float* __restrict__ wqr, const float* __restrict__ wqi,
    const float* __restrict__ wqj, const float* __restrict__ wqk,
    const float* __restrict__ wkr, const float* __restrict__ wki,
    const float* __restrict__ wkj, const float* __restrict__ wkk,
    const float* __restrict__ wv,  const float* __restrict__ wo,
    unsigned short* __restrict__ Wq, unsigned short* __restrict__ Wk,
    unsigned short* __restrict__ Wv, unsigned short* __restrict__ Wo)
{
  const int idx = blockIdx.x * 256 + threadIdx.x;   // over 1024*1024
  const int o = idx >> 10, i = idx & 1023;
  const int br = o >> 8, bc = i >> 8;
  const int ro = o & 255, ci = i & 255;
  const int comp[4][4] = {{0,1,2,3},{1,0,3,2},{2,3,0,1},{3,2,1,0}};
  const float sgn[4][4] = {{1.f,-1.f,-1.f,-1.f},{1.f,1.f,-1.f,1.f},{1.f,1.f,1.f,-1.f},{1.f,-1.f,1.f,1.f}};
  const float* pq[4] = {wqr, wqi, wqj, wqk};
  const float* pk[4] = {wkr, wki, wkj, wkk};
  const int c_ = comp[br][bc];
  const float s_ = sgn[br][bc];
  const int pidx = ro * 256 + ci;
  Wq[idx] = f2bf(s_ * pq[c_][pidx]);
  Wk[idx] = f2bf(s_ * pk[c_][pidx]);
  Wv[idx] = f2bf(wv[idx]);
  Wo[idx] = f2bf(wo[idx]);
}

// ---------------- prep: per-(b,n) spike threshold -> (kthr, limk) ----------------
__global__ __launch_bounds__(256) void prep_thr(
    const float* __restrict__ density, const float* __restrict__ dm1w,
    const float* __restrict__ dm1b, const float* __restrict__ dm2w,
    const float* __restrict__ dm2b, const float* __restrict__ thr_s,
    const int* __restrict__ mask, float2* __restrict__ out)
{
  const int i = blockIdx.x * 256 + threadIdx.x;  // over B*S = 4096
  if (i >= BB * SS) return;
  const float x0 = density[i*3+0], x1 = density[i*3+1], x2 = density[i*3+2];
  const float base = log1pf(expf(thr_s[0]));     // softplus
  float acc = dm2b[0];
  #pragma unroll
  for (int j = 0; j < 16; ++j) {
    const float hj = dm1w[j*3+0]*x0 + dm1w[j*3+1]*x1 + dm1w[j*3+2]*x2 + dm1b[j];
    const float ge = 0.5f * hj * (1.0f + erff(hj * 0.70710678118654752f)); // exact gelu
    acc += dm2w[j] * ge;
  }
  const float thr = base + 0.1f * acc;
  out[i] = make_float2(thr * (-C_NEG5L2E),            // +5*log2e*thr (exp2 arg offset)
                       mask[i] ? 1e30f : -30.0f);     // mask limit for min
}

// ---------------- GEMM: C(M=4096,N=1024) = A(M,K=1024) @ W(N,K)^T + bias ----------------
// A bf16, staged via global_load_lds (pre-swizzled source, linear LDS dest).
// DB=1: double-buffered LDS, one barrier per K-step. Batched over blockIdx.y.
// omode: 0 = bf16 row-major; 1 = bf16 per-head V^T (H,B,hd,S); 2 = fp32 row-major.
struct GemmArgs {
  const unsigned short* A[3];
  const unsigned short* W[3];
  const float* bias[3];
  void* out[3];
  float scale[3];
  int omode[3];
};

template<int DB>
__global__ __launch_bounds__(256) void gemm_bt(GemmArgs args)
{
  __shared__ __align__(16) unsigned short lA[DB + 1][128*64];
  __shared__ __align__(16) unsigned short lB[DB + 1][128*64];
  const int z = blockIdx.y;
  const int tid = threadIdx.x;
  const int wid = tid >> 6, lane = tid & 63;
  const int l15 = lane & 15, l4 = lane >> 4;
  // XCD-aware decode: same-bm blocks land on the same XCD (blockIdx % 8 == bm % 8)
  const int bm = blockIdx.x & 31, bn = blockIdx.x >> 5;
  const int row0 = bm * 128, col0 = bn * 128;
  const int wm = (wid >> 1) * 64, wn = (wid & 1) * 64;

  // per-lane pre-swizzled global sources; LDS dest linear so that final LDS
  // element layout is r*64 + ((j*8) ^ ((r&7)<<3))
  const unsigned short* gA[4];
  const unsigned short* gB[4];
  #pragma unroll
  for (int i = 0; i < 4; ++i) {
    const int c = (wid * 4 + i) * 64 + lane;
    const int r = c >> 3, jx = c & 7, j = jx ^ (r & 7);
    gA[i] = args.A[z] + (row0 + r) * 1024 + j * 8;
    gB[i] = args.W[z] + (col0 + r) * 1024 + j * 8;
  }

  f32x4 acc[4][4];
  #pragma unroll
  for (int i = 0; i < 4; ++i)
    #pragma unroll
    for (int j = 0; j < 4; ++j) acc[i][j] = (f32x4){0.f,0.f,0.f,0.f};

  // prologue: stage K-step 0 into buffer 0
  #pragma unroll
  for (int i = 0; i < 4; ++i) {
    gl16(gA[i], &lA[0][(wid * 4 + i) * 512]);
    gl16(gB[i], &lB[0][(wid * 4 + i) * 512]);
  }
  if (DB) __syncthreads();

  for (int kt = 0; kt < 16; ++kt) {
    const int cb = DB ? (kt & 1) : 0;
    if (DB) {
      if (kt < 15) {
        const int nb = cb ^ 1, k0 = (kt + 1) * 64;
        #pragma unroll
        for (int i = 0; i < 4; ++i) {
          gl16(gA[i] + k0, &lA[nb][(wid * 4 + i) * 512]);
          gl16(gB[i] + k0, &lB[nb][(wid * 4 + i) * 512]);
        }
      }
    } else {
      if (kt > 0) {
        const int k0 = kt * 64;
        #pragma unroll
        for (int i = 0; i < 4; ++i) {
          gl16(gA[i] + k0, &lA[0][(wid * 4 + i) * 512]);
          gl16(gB[i] + k0, &lB[0][(wid * 4 + i) * 512]);
        }
      }
      __syncthreads();
    }
    #pragma unroll
    for (int kk = 0; kk < 2; ++kk) {
      const int kl = kk * 32 + l4 * 8;
      bf16x8 af[4], bfb[4];
      #pragma unroll
      for (int mi = 0; mi < 4; ++mi) {
        const int r = wm + mi * 16 + l15;
        af[mi] = ldsv8(&lA[cb][r * 64 + (kl ^ ((r & 7) << 3))]);
      }
      #pragma unroll
      for (int nj = 0; nj < 4; ++nj) {
        const int r = wn + nj * 16 + l15;
        bfb[nj] = ldsv8(&lB[cb][r * 64 + (kl ^ ((r & 7) << 3))]);
      }
      #pragma unroll
      for (int mi = 0; mi < 4; ++mi)
        #pragma unroll
        for (int nj = 0; nj < 4; ++nj)
          acc[mi][nj] = MFMA16(af[mi], bfb[nj], acc[mi][nj]);
    }
    __syncthreads();
  }

  // epilogue: C/D layout col = lane&15, row = (lane>>4)*4 + e
  const int om = args.omode[z];
  const float sc = args.scale[z];
  void* Cptr = args.out[z];
  #pragma unroll
  for (int nj = 0; nj < 4; ++nj) {
    const int c = col0 + wn + nj * 16 + l15;
    const float bv_ = args.bias[z][c];
    #pragma unroll
    for (int mi = 0; mi < 4; ++mi) {
      const int rb = row0 + wm + mi * 16 + l4 * 4;
      #pragma unroll
      for (int e = 0; e < 4; ++e) {
        const float val = (acc[mi][nj][e] + bv_) * sc;
        const int r = rb + e;
        if (om == 0) {
          ((unsigned short*)Cptr)[r * 1024 + c] = f2bf(val);
        } else if (om == 2) {
          ((float*)Cptr)[r * 1024 + c] = val;
        } else {
          const int h = c >> 6, d = c & 63, b = r >> 11, s = r & 2047;
          ((unsigned short*)Cptr)[((h * BB + b) * HD + d) * SS + s] = f2bf(val);
        }
      }
    }
  }
}

// ---------------- flash attention with spike gate (fixed-max softmax) ----------------
__global__ __launch_bounds__(256) void attn_kernel(
    const unsigned short* __restrict__ qg, const unsigned short* __restrict__ kg,
    const unsigned short* __restrict__ vT, const float2* __restrict__ klim,
    const int* __restrict__ mask, unsigned short* __restrict__ outg)
{
  __shared__ __align__(16) unsigned short lK[2][64*64];
  __shared__ __align__(16) unsigned short lV[2][64*64];
  __shared__ __align__(16) unsigned short lP[4][16*64];
  const int tid = threadIdx.x;
  const int wid = tid >> 6, lane = tid & 63;
  const int l15 = lane & 15, l4 = lane >> 4;
  // XCD-aware decode: same-(h,b) blocks land on the same XCD -> K/V L2-resident
  const int hb = blockIdx.x & 31, qb = blockIdx.x >> 5;
  const int h = hb >> 1, b = hb & 1;
  const int qr0 = qb * 64 + wid * 16;

  // staging geometry: 512 chunks of 8 bf16 over a 64x64 tile, 2 per thread
  const int c0r = tid >> 3, c0j = (tid & 7) * 8;
  const int c1r = c0r + 32;
  const int dK0 = c0r * 64 + (c0j ^ ((c0r & 7) << 3));
  const int dK1 = c1r * 64 + (c0j ^ ((c1r & 7) << 3));
  const unsigned short* kbase = kg + (b * SS) * DM + h * HD;
  const unsigned short* vbase = vT + ((h * BB + b) * HD) * SS;
  const float2* klimb = klim + b * SS;

  // Q fragments in registers (A-frag: row=lane%16, k=(lane>>4)*8); Q pre-scaled by 0.25
  bf16x8 aq[2];
  {
    const unsigned short* qs = qg + (b * SS + qr0 + l15) * DM + h * HD + l4 * 8;
    aq[0] = __builtin_bit_cast(bf16x8, *(const u32x4*)qs);
    aq[1] = __builtin_bit_cast(bf16x8, *(const u32x4*)(qs + 32));
  }
  float limq[4];
  #pragma unroll
  for (int e = 0; e < 4; ++e)
    limq[e] = mask[b * SS + qr0 + l4 * 4 + e] ? 1e30f : -30.0f;

  float lrun[4] = {0.f, 0.f, 0.f, 0.f};
  f32x4 o[4];
  #pragma unroll
  for (int d = 0; d < 4; ++d) o[d] = (f32x4){0.f,0.f,0.f,0.f};

  unsigned short* lPw = lP[wid];

  // prologue: stage tile 0
  u32x4 kr0 = *(const u32x4*)(kbase + c0r * DM + c0j);
  u32x4 kr1 = *(const u32x4*)(kbase + c1r * DM + c0j);
  u32x4 vr0 = *(const u32x4*)(vbase + c0r * SS + c0j);
  u32x4 vr1 = *(const u32x4*)(vbase + c1r * SS + c0j);
  *(u32x4*)&lK[0][dK0] = kr0;
  *(u32x4*)&lK[0][dK1] = kr1;
  *(u32x4*)&lV[0][dK0] = vr0;
  *(u32x4*)&lV[0][dK1] = vr1;
  __syncthreads();

  for (int kb = 0; kb < 32; ++kb) {
    const int cur = kb & 1;
    const unsigned short* lKc = lK[cur];
    const unsigned short* lVc = lV[cur];
    const int n0g = kb * 64;

    // prefetch next tile into regs (hidden under compute)
    if (kb < 31) {
      const int n2 = n0g + 64;
      kr0 = *(const u32x4*)(kbase + (n2 + c0r) * DM + c0j);
      kr1 = *(const u32x4*)(kbase + (n2 + c1r) * DM + c0j);
      vr0 = *(const u32x4*)(vbase + c0r * SS + n2 + c0j);
      vr1 = *(const u32x4*)(vbase + c1r * SS + n2 + c0j);
    }

    // per-key (kthr, limk)
    float2 kl[4];
    #pragma unroll
    for (int cf = 0; cf < 4; ++cf) kl[cf] = klimb[n0g + cf * 16 + l15];

    // S = Q @ K^T (per wave: 16 rows x 64 cols)
    f32x4 sv[4];
    __builtin_amdgcn_s_setprio(1);
    #pragma unroll
    for (int cf = 0; cf < 4; ++cf) {
      f32x4 a = (f32x4){0.f,0.f,0.f,0.f};
      #pragma unroll
      for (int kk = 0; kk < 2; ++kk) {
        const int n = cf * 16 + l15;
        bf16x8 bk_ = ldsv8(&lKc[n * 64 + ((kk * 32 + l4 * 8) ^ ((n & 7) << 3))]);
        a = MFMA16(aq[kk], bk_, a);
      }
      sv[cf] = a;
    }
    __builtin_amdgcn_s_setprio(0);

    // spike gate + mask + fixed-max softmax numerator
    float pvv[4][4];
    #pragma unroll
    for (int cf = 0; cf < 4; ++cf) {
      #pragma unroll
      for (int e = 0; e < 4; ++e) {
        float s = fminf(fmaxf(sv[cf][e], -6.f), 6.f);
        const float t = __builtin_amdgcn_exp2f(fmaf(s, C_NEG5L2E, kl[cf].x));
        const float g = __builtin_amdgcn_rcpf(1.f + t);
        float md = fmaf(s + s, g, s);                       // s*(1+2g) in [-18,18]
        md = fminf(md, fminf(kl[cf].y, limq[e]));           // mask -> -30
        const float p = __builtin_amdgcn_exp2f(fmaf(md, C_L2E, -C_18L2E)); // exp(md-18)
        pvv[cf][e] = p;
        lrun[e] += p;
      }
    }

    // P -> per-wave LDS (swizzled), then A-fragments for PV
    #pragma unroll
    for (int cf = 0; cf < 4; ++cf)
      #pragma unroll
      for (int e = 0; e < 4; ++e) {
        const int rr = l4 * 4 + e, cc = cf * 16 + l15;
        lPw[rr * 64 + (cc ^ ((rr & 7) << 3))] = f2bf(pvv[cf][e]);
      }
    asm volatile("s_waitcnt lgkmcnt(0)" ::: "memory");
    __builtin_amdgcn_sched_barrier(0);

    bf16x8 pa[2];
    #pragma unroll
    for (int kk = 0; kk < 2; ++kk)
      pa[kk] = ldsv8(&lPw[l15 * 64 + ((kk * 32 + l4 * 8) ^ ((l15 & 7) << 3))]);

    __builtin_amdgcn_s_setprio(1);
    #pragma unroll
    for (int df = 0; df < 4; ++df) {
      #pragma unroll
      for (int kk = 0; kk < 2; ++kk) {
        const int d = df * 16 + l15;
        bf16x8 bv_ = ldsv8(&lVc[d * 64 + ((kk * 32 + l4 * 8) ^ ((d & 7) << 3))]);
        o[df] = MFMA16(pa[kk], bv_, o[df]);
      }
    }
    __builtin_amdgcn_s_setprio(0);

    // write next tile to the other LDS buffer
    if (kb < 31) {
      const int nxt = cur ^ 1;
      *(u32x4*)&lK[nxt][dK0] = kr0;
      *(u32x4*)&lK[nxt][dK1] = kr1;
      *(u32x4*)&lV[nxt][dK0] = vr0;
      *(u32x4*)&lV[nxt][dK1] = vr1;
    }
    __syncthreads();
  }

  // final: reduce row sums across the 16 lanes of each l4 group, normalize, store
  #pragma unroll
  for (int e = 0; e < 4; ++e) {
    float ls = lrun[e];
    ls += __shfl_xor(ls, 1);
    ls += __shfl_xor(ls, 2);
    ls += __shfl_xor(ls, 4);
    ls += __shfl_xor(ls, 8);
    const float rl = __builtin_amdgcn_rcpf(ls);
    const int r = qr0 + l4 * 4 + e;
    #pragma unroll
    for (int df = 0; df < 4; ++df) {
      outg[(b * SS + r) * DM + h * HD + df * 16 + l15] = f2bf(o[df][e] * rl);
    }
  }
}

// ---------------- launcher ----------------
extern "C" void kernel_launch(void* const* d_in, const int* in_sizes, int n_in,
                              void* d_out, int out_size, void* d_ws, size_t ws_size,
                              hipStream_t stream)
{
  const float* query   = (const float*)d_in[0];
  const float* key_in  = (const float*)d_in[1];
  const float* value   = (const float*)d_in[2];
  const int*   mask    = (const int*)d_in[3];
  const float* density = (const float*)d_in[4];
  const float* wq_r = (const float*)d_in[5];
  const float* wq_i = (const float*)d_in[6];
  const float* wq_j = (const float*)d_in[7];
  const float* wq_k = (const float*)d_in[8];
  const float* bq   = (const float*)d_in[9];
  const float* wk_r = (const float*)d_in[10];
  const float* wk_i = (const float*)d_in[11];
  const float* wk_j = (const float*)d_in[12];
  const float* wk_k = (const float*)d_in[13];
  const float* bk   = (const float*)d_in[14];
  const float* wv   = (const float*)d_in[15];
  const float* bv   = (const float*)d_in[16];
  const float* wo   = (const float*)d_in[17];
  const float* bo   = (const float*)d_in[18];
  const float* thrs = (const float*)d_in[19];
  const float* dm1w = (const float*)d_in[20];
  const float* dm1b = (const float*)d_in[21];
  const float* dm2w = (const float*)d_in[22];
  const float* dm2b = (const float*)d_in[23];

  char* ws = (char*)d_ws;
  unsigned short* Wq  = (unsigned short*)(ws + ((size_t)0 << 20));
  unsigned short* Wk  = (unsigned short*)(ws + ((size_t)2 << 20));
  unsigned short* Wv  = (unsigned short*)(ws + ((size_t)4 << 20));
  unsigned short* Wo  = (unsigned short*)(ws + ((size_t)6 << 20));
  unsigned short* qbf = (unsigned short*)(ws + ((size_t)8 << 20));
  unsigned short* kbf = (unsigned short*)(ws + ((size_t)16 << 20));
  unsigned short* vT  = (unsigned short*)(ws + ((size_t)24 << 20));
  unsigned short* att = (unsigned short*)(ws + ((size_t)32 << 20));
  float2* klim        = (float2*)(ws + ((size_t)40 << 20));

  // bf16 converts of activations: q/k live in d_out (overwritten by final GEMM
  // after consumption), v lives in the att region (written by attn after use).
  unsigned short* qcv = (unsigned short*)d_out;
  unsigned short* kcv = (unsigned short*)d_out + (size_t)MTOT * DM;
  unsigned short* vcv = att;

  cvt_bf16<<<2048, 256, 0, stream>>>(query, key_in, value, qcv, kcv, vcv);
  prep_w<<<4096, 256, 0, stream>>>(wq_r, wq_i, wq_j, wq_k,
                                   wk_r, wk_i, wk_j, wk_k,
                                   wv, wo, Wq, Wk, Wv, Wo);
  prep_thr<<<16, 256, 0, stream>>>(density, dm1w, dm1b, dm2w, dm2b, thrs, mask, klim);

  GemmArgs qkv;
  qkv.A[0] = qcv; qkv.W[0] = Wq; qkv.bias[0] = bq; qkv.out[0] = qbf; qkv.scale[0] = 0.25f; qkv.omode[0] = 0;
  qkv.A[1] = kcv; qkv.W[1] = Wk; qkv.bias[1] = bk; qkv.out[1] = kbf; qkv.scale[1] = 1.0f;  qkv.omode[1] = 0;
  qkv.A[2] = vcv; qkv.W[2] = Wv; qkv.bias[2] = bv; qkv.out[2] = vT;  qkv.scale[2] = 1.0f;  qkv.omode[2] = 1;
  gemm_bt<0><<<dim3(256, 3), 256, 0, stream>>>(qkv);

  attn_kernel<<<1024, 256, 0, stream>>>(qbf, kbf, vT, klim, mask, att);

  GemmArgs og;
  og.A[0] = att; og.W[0] = Wo; og.bias[0] = bo; og.out[0] = d_out; og.scale[0] = 1.0f; og.omode[0] = 2;
  og.A[1] = att; og.W[1] = Wo; og.bias[1] = bo; og.out[1] = d_out; og.scale[1] = 1.0f; og.omode[1] = 2;
  og.A[2] = att; og.W[2] = Wo; og.bias[2] = bo; og.out[2] = d_out; og.scale[2] = 1.0f; og.omode[2] = 2;
  gemm_bt<1><<<dim3(256, 1), 256, 0, stream>>>(og);
}

// Round 5
// 188.251 us; speedup vs baseline: 1.1566x; 1.0106x over previous
//
#include <hip/hip_runtime.h>
#include <stdint.h>
#include <math.h>

#define BB 2
#define SS 2048
#define DM 1024
#define NH 16
#define HD 64
#define MTOT (BB*SS)

typedef __bf16 bf16x8 __attribute__((ext_vector_type(8)));
typedef float  f32x4  __attribute__((ext_vector_type(4)));
typedef uint32_t u32x4 __attribute__((ext_vector_type(4)));

__device__ __forceinline__ unsigned short f2bf(float f) {
  __bf16 h = (__bf16)f;                 // RNE; compiler packs to v_cvt_pk_bf16_f32
  return __builtin_bit_cast(unsigned short, h);
}

__device__ __forceinline__ bf16x8 ldsv8(const unsigned short* p) {
  return __builtin_bit_cast(bf16x8, *(const u32x4*)p);
}

__device__ __forceinline__ void gl16(const void* g, void* l) {
  __builtin_amdgcn_global_load_lds(
      (const __attribute__((address_space(1))) uint32_t*)g,
      (__attribute__((address_space(3))) uint32_t*)l, 16, 0, 0);
}

#define MFMA16(a,b,c) __builtin_amdgcn_mfma_f32_16x16x32_bf16((a),(b),(c),0,0,0)

// gate/softmax constants
#define C_NEG5L2E  (-7.213475204444817f)   // -5*log2(e)
#define C_L2E      (1.4426950408889634f)   // log2(e)
#define C_18L2E    (25.968510736001341f)   // 18*log2(e)

// ---------------- prep: fp32 -> bf16 convert of q/k/v activations ----------------
__global__ __launch_bounds__(256) void cvt_bf16(
    const float* __restrict__ a, const float* __restrict__ b, const float* __restrict__ c,
    unsigned short* __restrict__ ao, unsigned short* __restrict__ bo, unsigned short* __restrict__ co)
{
  const int i8 = (blockIdx.x * 256 + threadIdx.x) * 8;   // grid covers 4194304 elems
  {
    const float4 f0 = *(const float4*)(a + i8);
    const float4 f1 = *(const float4*)(a + i8 + 4);
    union { unsigned short us[8]; u32x4 v; } t;
    t.us[0]=f2bf(f0.x); t.us[1]=f2bf(f0.y); t.us[2]=f2bf(f0.z); t.us[3]=f2bf(f0.w);
    t.us[4]=f2bf(f1.x); t.us[5]=f2bf(f1.y); t.us[6]=f2bf(f1.z); t.us[7]=f2bf(f1.w);
    *(u32x4*)(ao + i8) = t.v;
  }
  {
    const float4 f0 = *(const float4*)(b + i8);
    const float4 f1 = *(const float4*)(b + i8 + 4);
    union { unsigned short us[8]; u32x4 v; } t;
    t.us[0]=f2bf(f0.x); t.us[1]=f2bf(f0.y); t.us[2]=f2bf(f0.z); t.us[3]=f2bf(f0.w);
    t.us[4]=f2bf(f1.x); t.us[5]=f2bf(f1.y); t.us[6]=f2bf(f1.z); t.us[7]=f2bf(f1.w);
    *(u32x4*)(bo + i8) = t.v;
  }
  {
    const float4 f0 = *(const float4*)(c + i8);
    const float4 f1 = *(const float4*)(c + i8 + 4);
    union { unsigned short us[8]; u32x4 v; } t;
    t.us[0]=f2bf(f0.x); t.us[1]=f2bf(f0.y); t.us[2]=f2bf(f0.z); t.us[3]=f2bf(f0.w);
    t.us[4]=f2bf(f1.x); t.us[5]=f2bf(f1.y); t.us[6]=f2bf(f1.z); t.us[7]=f2bf(f1.w);
    *(u32x4*)(co + i8) = t.v;
  }
}

// ---------------- prep: quaternion weight build + bf16 conversion ----------------
__global__ __launch_bounds__(256) void prep_w(
    const float* __restrict__ wqr, const float* __restrict__ wqi,
    const float* __restrict__ wqj, const float* __restrict__ wqk,
    const float* __restrict__ wkr, const float* __restrict__ wki,
    const float* __restrict__ wkj, const float* __restrict__ wkk,
    const float* __restrict__ wv,  const float* __restrict__ wo,
    unsigned short* __restrict__ Wq, unsigned short* __restrict__ Wk,
    unsigned short* __restrict__ Wv, unsigned short* __restrict__ Wo)
{
  const int idx = blockIdx.x * 256 + threadIdx.x;   // over 1024*1024
  const int o = idx >> 10, i = idx & 1023;
  const int br = o >> 8, bc = i >> 8;
  const int ro = o & 255, ci = i & 255;
  const int comp[4][4] = {{0,1,2,3},{1,0,3,2},{2,3,0,1},{3,2,1,0}};
  const float sgn[4][4] = {{1.f,-1.f,-1.f,-1.f},{1.f,1.f,-1.f,1.f},{1.f,1.f,1.f,-1.f},{1.f,-1.f,1.f,1.f}};
  const float* pq[4] = {wqr, wqi, wqj, wqk};
  const float* pk[4] = {wkr, wki, wkj, wkk};
  const int c_ = comp[br][bc];
  const float s_ = sgn[br][bc];
  const int pidx = ro * 256 + ci;
  Wq[idx] = f2bf(s_ * pq[c_][pidx]);
  Wk[idx] = f2bf(s_ * pk[c_][pidx]);
  Wv[idx] = f2bf(wv[idx]);
  Wo[idx] = f2bf(wo[idx]);
}

// ---------------- prep: per-(b,n) spike threshold -> (kthr, limk) ----------------
__global__ __launch_bounds__(256) void prep_thr(
    const float* __restrict__ density, const float* __restrict__ dm1w,
    const float* __restrict__ dm1b, const float* __restrict__ dm2w,
    const float* __restrict__ dm2b, const float* __restrict__ thr_s,
    const int* __restrict__ mask, float2* __restrict__ out)
{
  const int i = blockIdx.x * 256 + threadIdx.x;  // over B*S = 4096
  if (i >= BB * SS) return;
  const float x0 = density[i*3+0], x1 = density[i*3+1], x2 = density[i*3+2];
  const float base = log1pf(expf(thr_s[0]));     // softplus
  float acc = dm2b[0];
  #pragma unroll
  for (int j = 0; j < 16; ++j) {
    const float hj = dm1w[j*3+0]*x0 + dm1w[j*3+1]*x1 + dm1w[j*3+2]*x2 + dm1b[j];
    const float ge = 0.5f * hj * (1.0f + erff(hj * 0.70710678118654752f)); // exact gelu
    acc += dm2w[j] * ge;
  }
  const float thr = base + 0.1f * acc;
  out[i] = make_float2(thr * (-C_NEG5L2E),            // +5*log2e*thr (exp2 arg offset)
                       mask[i] ? 1e30f : -30.0f);     // mask limit for min
}

// ---------------- GEMM: C(M=4096,N=1024) = A(M,K=1024) @ W(N,K)^T + bias ----------------
struct GemmArgs {
  const unsigned short* A[3];
  const unsigned short* W[3];
  const float* bias[3];
  void* out[3];
  float scale[3];
  int omode[3];
};

template<int DB>
__global__ __launch_bounds__(256) void gemm_bt(GemmArgs args)
{
  __shared__ __align__(16) unsigned short lA[DB + 1][128*64];
  __shared__ __align__(16) unsigned short lB[DB + 1][128*64];
  const int z = blockIdx.y;
  const int tid = threadIdx.x;
  const int wid = tid >> 6, lane = tid & 63;
  const int l15 = lane & 15, l4 = lane >> 4;
  const int bm = blockIdx.x & 31, bn = blockIdx.x >> 5;   // XCD-aware decode
  const int row0 = bm * 128, col0 = bn * 128;
  const int wm = (wid >> 1) * 64, wn = (wid & 1) * 64;

  const unsigned short* gA[4];
  const unsigned short* gB[4];
  #pragma unroll
  for (int i = 0; i < 4; ++i) {
    const int c = (wid * 4 + i) * 64 + lane;
    const int r = c >> 3, jx = c & 7, j = jx ^ (r & 7);
    gA[i] = args.A[z] + (row0 + r) * 1024 + j * 8;
    gB[i] = args.W[z] + (col0 + r) * 1024 + j * 8;
  }

  f32x4 acc[4][4];
  #pragma unroll
  for (int i = 0; i < 4; ++i)
    #pragma unroll
    for (int j = 0; j < 4; ++j) acc[i][j] = (f32x4){0.f,0.f,0.f,0.f};

  #pragma unroll
  for (int i = 0; i < 4; ++i) {
    gl16(gA[i], &lA[0][(wid * 4 + i) * 512]);
    gl16(gB[i], &lB[0][(wid * 4 + i) * 512]);
  }
  if (DB) __syncthreads();

  for (int kt = 0; kt < 16; ++kt) {
    const int cb = DB ? (kt & 1) : 0;
    if (DB) {
      if (kt < 15) {
        const int nb = cb ^ 1, k0 = (kt + 1) * 64;
        #pragma unroll
        for (int i = 0; i < 4; ++i) {
          gl16(gA[i] + k0, &lA[nb][(wid * 4 + i) * 512]);
          gl16(gB[i] + k0, &lB[nb][(wid * 4 + i) * 512]);
        }
      }
    } else {
      if (kt > 0) {
        const int k0 = kt * 64;
        #pragma unroll
        for (int i = 0; i < 4; ++i) {
          gl16(gA[i] + k0, &lA[0][(wid * 4 + i) * 512]);
          gl16(gB[i] + k0, &lB[0][(wid * 4 + i) * 512]);
        }
      }
      __syncthreads();
    }
    #pragma unroll
    for (int kk = 0; kk < 2; ++kk) {
      const int kl = kk * 32 + l4 * 8;
      bf16x8 af[4], bfb[4];
      #pragma unroll
      for (int mi = 0; mi < 4; ++mi) {
        const int r = wm + mi * 16 + l15;
        af[mi] = ldsv8(&lA[cb][r * 64 + (kl ^ ((r & 7) << 3))]);
      }
      #pragma unroll
      for (int nj = 0; nj < 4; ++nj) {
        const int r = wn + nj * 16 + l15;
        bfb[nj] = ldsv8(&lB[cb][r * 64 + (kl ^ ((r & 7) << 3))]);
      }
      #pragma unroll
      for (int mi = 0; mi < 4; ++mi)
        #pragma unroll
        for (int nj = 0; nj < 4; ++nj)
          acc[mi][nj] = MFMA16(af[mi], bfb[nj], acc[mi][nj]);
    }
    __syncthreads();
  }

  const int om = args.omode[z];
  const float sc = args.scale[z];
  void* Cptr = args.out[z];
  #pragma unroll
  for (int nj = 0; nj < 4; ++nj) {
    const int c = col0 + wn + nj * 16 + l15;
    const float bv_ = args.bias[z][c];
    #pragma unroll
    for (int mi = 0; mi < 4; ++mi) {
      const int rb = row0 + wm + mi * 16 + l4 * 4;
      #pragma unroll
      for (int e = 0; e < 4; ++e) {
        const float val = (acc[mi][nj][e] + bv_) * sc;
        const int r = rb + e;
        if (om == 0) {
          ((unsigned short*)Cptr)[r * 1024 + c] = f2bf(val);
        } else if (om == 2) {
          ((float*)Cptr)[r * 1024 + c] = val;
        } else {
          const int h = c >> 6, d = c & 63, b = r >> 11, s = r & 2047;
          ((unsigned short*)Cptr)[((h * BB + b) * HD + d) * SS + s] = f2bf(val);
        }
      }
    }
  }
}

// ---------------- flash attention with spike gate: split-K wave pairs ----------------
// 512 threads = 8 waves = 4 row-groups x 2 key-parities. Per pair-interval (64 keys),
// wave (rg,par) computes the 32-key tile of its parity; partials merged at the end
// (valid because softmax uses a fixed max). 32 waves/CU target.
__global__ __launch_bounds__(512) void attn_kernel(
    const unsigned short* __restrict__ qg, const unsigned short* __restrict__ kg,
    const unsigned short* __restrict__ vT, const float2* __restrict__ klim,
    const int* __restrict__ mask, unsigned short* __restrict__ outg)
{
  __shared__ __align__(16) unsigned short smem[20480];   // 40 KB
  unsigned short* lK = smem;            // [pairbuf 2][tile 2][32 key-rows][64 hd]
  unsigned short* lV = smem + 8192;     // [pairbuf 2][tile 2][64 d-rows][32 keys]
  unsigned short* lP = smem + 16384;    // [wave 8][16 qrows][32 keys]

  const int tid = threadIdx.x;
  const int wid = tid >> 6, lane = tid & 63;
  const int l15 = lane & 15, l4 = lane >> 4;
  const int rg = wid >> 1, par = wid & 1;
  const int hb = blockIdx.x & 31, qb = blockIdx.x >> 5;  // XCD: same (h,b) -> same XCD
  const int h = hb >> 1, b = hb & 1;
  const int qr0 = qb * 64 + rg * 16;

  // staging: each thread 1 K-chunk + 1 V-chunk of the 64-key pair
  const int kcr = tid >> 3, kcj = (tid & 7) * 8;         // K: key row, hd col
  const int vcd = tid >> 3, vck = (tid & 7) * 8;         // V: d row, key col
  const int kdst = (kcr >> 5) * 2048 + (kcr & 31) * 64 + (kcj ^ ((((kcr & 31) >> 1) & 7) << 3));
  const int vdst = (vck >> 5) * 2048 + vcd * 32 + ((vck & 31) ^ ((vcd & 3) << 3));

  const unsigned short* kbase = kg + (b * SS) * DM + h * HD;
  const unsigned short* vbase = vT + ((h * BB + b) * HD) * SS;
  const float2* klimb = klim + b * SS;

  // Q fragments (A-frag: row=lane%16, k=(lane>>4)*8); Q pre-scaled by 0.25
  bf16x8 aq[2];
  {
    const unsigned short* qs = qg + (b * SS + qr0 + l15) * DM + h * HD + l4 * 8;
    aq[0] = __builtin_bit_cast(bf16x8, *(const u32x4*)qs);
    aq[1] = __builtin_bit_cast(bf16x8, *(const u32x4*)(qs + 32));
  }
  float limq[4];
  #pragma unroll
  for (int e = 0; e < 4; ++e)
    limq[e] = mask[b * SS + qr0 + l4 * 4 + e] ? 1e30f : -30.0f;

  float lrun[4] = {0.f, 0.f, 0.f, 0.f};
  f32x4 o[4];
  #pragma unroll
  for (int d = 0; d < 4; ++d) o[d] = (f32x4){0.f,0.f,0.f,0.f};

  unsigned short* lPw = lP + wid * 512;

  // prologue: stage pair 0
  u32x4 kr = *(const u32x4*)(kbase + kcr * DM + kcj);
  u32x4 vr = *(const u32x4*)(vbase + vcd * SS + vck);
  *(u32x4*)&lK[kdst] = kr;
  *(u32x4*)&lV[vdst] = vr;
  __syncthreads();

  for (int pr = 0; pr < 32; ++pr) {
    const int cur = pr & 1;
    const unsigned short* lKt = lK + cur * 4096 + par * 2048;
    const unsigned short* lVt = lV + cur * 4096 + par * 2048;
    const int n0 = pr * 64 + par * 32;

    if (pr < 31) {
      const int nn = (pr + 1) * 64;
      kr = *(const u32x4*)(kbase + (nn + kcr) * DM + kcj);
      vr = *(const u32x4*)(vbase + vcd * SS + nn + vck);
    }

    const float4 klA = *(const float4*)(klimb + n0 + 2 * l15);   // keys 2l15, 2l15+1

    // S = Q @ K^T : key = 2*l15 + cf
    f32x4 sv[2];
    __builtin_amdgcn_s_setprio(1);
    #pragma unroll
    for (int cf = 0; cf < 2; ++cf) {
      f32x4 a = (f32x4){0.f,0.f,0.f,0.f};
      const int r = 2 * l15 + cf;
      #pragma unroll
      for (int kk = 0; kk < 2; ++kk)
        a = MFMA16(aq[kk], ldsv8(&lKt[r * 64 + ((kk * 32 + l4 * 8) ^ ((l15 & 7) << 3))]), a);
      sv[cf] = a;
    }
    __builtin_amdgcn_s_setprio(0);

    // spike gate + mask + fixed-max softmax numerator
    float pvv[2][4];
    #pragma unroll
    for (int cf = 0; cf < 2; ++cf) {
      const float kth = cf ? klA.z : klA.x;
      const float klm = cf ? klA.w : klA.y;
      #pragma unroll
      for (int e = 0; e < 4; ++e) {
        float s = fminf(fmaxf(sv[cf][e], -6.f), 6.f);
        const float t = __builtin_amdgcn_exp2f(fmaf(s, C_NEG5L2E, kth));
        const float g = __builtin_amdgcn_rcpf(1.f + t);
        float md = fmaf(s + s, g, s);                       // s*(1+2g) in [-18,18]
        md = fminf(md, fminf(klm, limq[e]));                // mask -> -30
        const float p = __builtin_amdgcn_exp2f(fmaf(md, C_L2E, -C_18L2E)); // exp(md-18)
        pvv[cf][e] = p;
        lrun[e] += p;
      }
    }

    // P -> per-wave LDS: packed pair writes (keys 2l15, 2l15+1)
    #pragma unroll
    for (int e = 0; e < 4; ++e) {
      const int rr = l4 * 4 + e;
      union { unsigned short us[2]; unsigned int u; } pk2;
      pk2.us[0] = f2bf(pvv[0][e]);
      pk2.us[1] = f2bf(pvv[1][e]);
      *(unsigned int*)&lPw[rr * 32 + ((2 * l15) ^ ((rr & 3) << 3))] = pk2.u;
    }
    asm volatile("s_waitcnt lgkmcnt(0)" ::: "memory");
    __builtin_amdgcn_sched_barrier(0);

    const bf16x8 pa = ldsv8(&lPw[l15 * 32 + ((l4 * 8) ^ ((l15 & 3) << 3))]);

    __builtin_amdgcn_s_setprio(1);
    #pragma unroll
    for (int df = 0; df < 4; ++df) {
      const int d = df * 16 + l15;
      o[df] = MFMA16(pa, ldsv8(&lVt[d * 32 + ((l4 * 8) ^ ((d & 3) << 3))]), o[df]);
    }
    __builtin_amdgcn_s_setprio(0);

    if (pr < 31) {
      const int nxt = cur ^ 1;
      *(u32x4*)&lK[nxt * 4096 + kdst] = kr;
      *(u32x4*)&lV[nxt * 4096 + vdst] = vr;
    }
    __syncthreads();
  }

  // merge parity partials via LDS (smem reuse), normalize, store
  __syncthreads();
  float* xch = (float*)smem;
  float* slot = xch + rg * 1280;
  if (par) {
    #pragma unroll
    for (int df = 0; df < 4; ++df)
      *(f32x4*)&slot[(df * 64 + lane) * 4] = o[df];
    f32x4 lr;
    lr[0] = lrun[0]; lr[1] = lrun[1]; lr[2] = lrun[2]; lr[3] = lrun[3];
    *(f32x4*)&slot[1024 + lane * 4] = lr;
  }
  __syncthreads();
  if (!par) {
    #pragma unroll
    for (int df = 0; df < 4; ++df) {
      const f32x4 t = *(const f32x4*)&slot[(df * 64 + lane) * 4];
      o[df][0] += t[0]; o[df][1] += t[1]; o[df][2] += t[2]; o[df][3] += t[3];
    }
    const f32x4 lr = *(const f32x4*)&slot[1024 + lane * 4];
    #pragma unroll
    for (int e = 0; e < 4; ++e) {
      float ls = lrun[e] + lr[e];
      ls += __shfl_xor(ls, 1);
      ls += __shfl_xor(ls, 2);
      ls += __shfl_xor(ls, 4);
      ls += __shfl_xor(ls, 8);
      const float rl = __builtin_amdgcn_rcpf(ls);
      const int r = qr0 + l4 * 4 + e;
      #pragma unroll
      for (int df = 0; df < 4; ++df) {
        outg[(b * SS + r) * DM + h * HD + df * 16 + l15] = f2bf(o[df][e] * rl);
      }
    }
  }
}

// ---------------- launcher ----------------
extern "C" void kernel_launch(void* const* d_in, const int* in_sizes, int n_in,
                              void* d_out, int out_size, void* d_ws, size_t ws_size,
                              hipStream_t stream)
{
  const float* query   = (const float*)d_in[0];
  const float* key_in  = (const float*)d_in[1];
  const float* value   = (const float*)d_in[2];
  const int*   mask    = (const int*)d_in[3];
  const float* density = (const float*)d_in[4];
  const float* wq_r = (const float*)d_in[5];
  const float* wq_i = (const float*)d_in[6];
  const float* wq_j = (const float*)d_in[7];
  const float* wq_k = (const float*)d_in[8];
  const float* bq   = (const float*)d_in[9];
  const float* wk_r = (const float*)d_in[10];
  const float* wk_i = (const float*)d_in[11];
  const float* wk_j = (const float*)d_in[12];
  const float* wk_k = (const float*)d_in[13];
  const float* bk   = (const float*)d_in[14];
  const float* wv   = (const float*)d_in[15];
  const float* bv   = (const float*)d_in[16];
  const float* wo   = (const float*)d_in[17];
  const float* bo   = (const float*)d_in[18];
  const float* thrs = (const float*)d_in[19];
  const float* dm1w = (const float*)d_in[20];
  const float* dm1b = (const float*)d_in[21];
  const float* dm2w = (const float*)d_in[22];
  const float* dm2b = (const float*)d_in[23];

  char* ws = (char*)d_ws;
  unsigned short* Wq  = (unsigned short*)(ws + ((size_t)0 << 20));
  unsigned short* Wk  = (unsigned short*)(ws + ((size_t)2 << 20));
  unsigned short* Wv  = (unsigned short*)(ws + ((size_t)4 << 20));
  unsigned short* Wo  = (unsigned short*)(ws + ((size_t)6 << 20));
  unsigned short* qbf = (unsigned short*)(ws + ((size_t)8 << 20));
  unsigned short* kbf = (unsigned short*)(ws + ((size_t)16 << 20));
  unsigned short* vT  = (unsigned short*)(ws + ((size_t)24 << 20));
  unsigned short* att = (unsigned short*)(ws + ((size_t)32 << 20));
  float2* klim        = (float2*)(ws + ((size_t)40 << 20));

  unsigned short* qcv = (unsigned short*)d_out;
  unsigned short* kcv = (unsigned short*)d_out + (size_t)MTOT * DM;
  unsigned short* vcv = att;

  cvt_bf16<<<2048, 256, 0, stream>>>(query, key_in, value, qcv, kcv, vcv);
  prep_w<<<4096, 256, 0, stream>>>(wq_r, wq_i, wq_j, wq_k,
                                   wk_r, wk_i, wk_j, wk_k,
                                   wv, wo, Wq, Wk, Wv, Wo);
  prep_thr<<<16, 256, 0, stream>>>(density, dm1w, dm1b, dm2w, dm2b, thrs, mask, klim);

  GemmArgs qkv;
  qkv.A[0] = qcv; qkv.W[0] = Wq; qkv.bias[0] = bq; qkv.out[0] = qbf; qkv.scale[0] = 0.25f; qkv.omode[0] = 0;
  qkv.A[1] = kcv; qkv.W[1] = Wk; qkv.bias[1] = bk; qkv.out[1] = kbf; qkv.scale[1] = 1.0f;  qkv.omode[1] = 0;
  qkv.A[2] = vcv; qkv.W[2] = Wv; qkv.bias[2] = bv; qkv.out[2] = vT;  qkv.scale[2] = 1.0f;  qkv.omode[2] = 1;
  gemm_bt<0><<<dim3(256, 3), 256, 0, stream>>>(qkv);

  attn_kernel<<<1024, 512, 0, stream>>>(qbf, kbf, vT, klim, mask, att);

  GemmArgs og;
  og.A[0] = att; og.W[0] = Wo; og.bias[0] = bo; og.out[0] = d_out; og.scale[0] = 1.0f; og.omode[0] = 2;
  og.A[1] = att; og.W[1] = Wo; og.bias[1] = bo; og.out[1] = d_out; og.scale[1] = 1.0f; og.omode[1] = 2;
  og.A[2] = att; og.W[2] = Wo; og.bias[2] = bo; og.out[2] = d_out; og.scale[2] = 1.0f; og.omode[2] = 2;
  gemm_bt<1><<<dim3(256, 1), 256, 0, stream>>>(og);
}